// Round 2
// baseline (355.423 us; speedup 1.0000x reference)
//
#include <hip/hip_runtime.h>

// ---------------------------------------------------------------------------
// B=8, N=128, XD=256, ED=128, H=8, DF=32, FFX=1024, FFE=512. All I/O fp32.
// softmax over axis=1 + (attn*V).sum(1) collapses to V => newX = (x@wv+bv)@wxo+bxo.
// bf16 MFMA 16x16x32, fp32 accumulate. Verified layouts:
//   A-frag: lane holds A[m=lane&15][k=(lane>>4)*8 + j], j=0..7
//   B-frag: lane holds B[k=(lane>>4)*8+j][n=lane&15]  (pre-packed contiguous)
//   C/D   : col=lane&15, row=(lane>>4)*4 + reg
// Round 6: 3 launches; x-path remainder runs in blocks 0..63 of fused_main.
// Round 7: register-blocked e-path (weights loaded once per wave; A-frags
// cached across nt).
// Round 8: occupancy 3->4 blocks/CU. LDS 51200->34304 via FF quarters
// (H1 buffer 16896->8704), liveness aliasing (sYb->sTb->sH2 share one region;
// sR->sH1 share another), and bf16 residuals (sR/sRx/sH2x; |newE|,|H2| << |e|
// so rounding adds <1e-3 pre-LN). __launch_bounds__(256,4) caps VGPR at 128.
// ---------------------------------------------------------------------------

#define RSQRT_DF 0.17677669529663687f  // 1/sqrt(32)

typedef __attribute__((ext_vector_type(8))) short short8;
typedef __attribute__((ext_vector_type(4))) short short4v;
typedef __attribute__((ext_vector_type(4))) float f32x4;

__device__ __forceinline__ short f2bs(float f) {  // fp32->bf16 bits, RNE
    unsigned u = __float_as_uint(f);
    unsigned r = u + 0x7FFFu + ((u >> 16) & 1u);
    return (short)(r >> 16);
}
__device__ __forceinline__ float bs2f(short s) {  // bf16 bits->fp32
    return __uint_as_float(((unsigned)(unsigned short)s) << 16);
}

// ---------------- single-launch weight pack (all 11 weights) ----------------
struct PackArgs {
    const float* W[11];
    short* Wp[11];
    int kdiv[11];   // K/32
    int N[11];
    int start[12];  // prefix sums of per-weight group counts; start[11]=total
};

__global__ __launch_bounds__(256) void pack_all(PackArgs pa) {
    int g = blockIdx.x * 256 + threadIdx.x;
    if (g >= pa.start[11]) return;
    int i = 0;
    while (g >= pa.start[i + 1]) ++i;
    int local = g - pa.start[i];
    int kdiv = pa.kdiv[i], N = pa.N[i];
    int lane = local & 63, rest = local >> 6;
    int kb = rest % kdiv, nt = rest / kdiv;
    int n = nt * 16 + (lane & 15);
    int k0 = kb * 32 + ((lane >> 4) << 3);
    const float* W = pa.W[i];
    short8 v;
#pragma unroll
    for (int j = 0; j < 8; ++j) v[j] = f2bs(W[(size_t)(k0 + j) * N + n]);
    *(short8*)(pa.Wp[i] + (size_t)local * 8) = v;
}

// ---------------- Q/K GEMM (feeds e-path) ----------------------------------
__global__ __launch_bounds__(256) void qk_gemm(
    const float* __restrict__ x,
    const short* __restrict__ wqP, const short* __restrict__ wkP,
    const float* __restrict__ bq, const float* __restrict__ bk,
    float* __restrict__ Qb, float* __restrict__ Kb) {
    __shared__ short sXb[16 * 264];
    const int t = threadIdx.x, wave = t >> 6, lane = t & 63;
    const int quad = lane >> 4, l15 = lane & 15;
    const int m0 = (blockIdx.x & 63) * 16;
    const int isK = blockIdx.x >> 6;
    const short* wP = isK ? wkP : wqP;
    const float* bp = isK ? bk : bq;
    float* outp = isK ? Kb : Qb;

    const float4* x4 = (const float4*)(x + (size_t)m0 * 256);
    for (int g = t; g < 1024; g += 256) {
        float4 v = x4[g];
        int row = g >> 6, col4 = (g & 63) * 4;
        short4v sv = {f2bs(v.x), f2bs(v.y), f2bs(v.z), f2bs(v.w)};
        *(short4v*)(sXb + row * 264 + col4) = sv;
    }
    __syncthreads();

#pragma unroll 2
    for (int p = 0; p < 4; ++p) {
        int nt = wave * 4 + p;
        f32x4 acc = (f32x4){0.f, 0.f, 0.f, 0.f};
        const short* aB = sXb + l15 * 264 + quad * 8;
        const short* bB = wP + ((size_t)(nt * 8) * 64 + lane) * 8;
#pragma unroll
        for (int kb = 0; kb < 8; ++kb) {
            short8 a = *(const short8*)(aB + kb * 32);
            short8 w = *(const short8*)(bB + (size_t)kb * 512);
            acc = __builtin_amdgcn_mfma_f32_16x16x32_bf16(a, w, acc, 0, 0, 0);
        }
        int col = nt * 16 + l15;
        float bvv = bp[col];
#pragma unroll
        for (int r = 0; r < 4; ++r)
            outp[(size_t)(m0 + quad * 4 + r) * 256 + col] = acc[r] + bvv;
    }
}

// ---------------- fused main: 64 x-rest blocks + 4096 e-path blocks --------
// LDS 34304 B -> 4 blocks/CU (137216 <= 163840). VGPR capped 128 (4 w/SIMD).
// e-path: sEb@0 [32][136] 8704 | R3@8704 16896: sYb[32][264] -> sTb[32][136]
//         -> sH2 f32 [32][132] | R2@25600 8704: sR[32][136] bf16 -> sH1[32][136]
// x-path: sXb@0 8448 | sVb@8448 8448 | sTbx@16896 8448 |
//         R@25344 8448: sRx bf16 -> sH1x quarter -> sH2x bf16   (33792 total)
__global__ __launch_bounds__(256, 4) void fused_main(
    const float* __restrict__ x, const float* __restrict__ e,
    const float* __restrict__ Qb, const float* __restrict__ Kb,
    const short* __restrict__ wvP, const short* __restrict__ wxoP,
    const short* __restrict__ wx1P, const short* __restrict__ wx2P,
    const short* __restrict__ wemP, const short* __restrict__ weaP,
    const short* __restrict__ weoP, const short* __restrict__ we1P,
    const short* __restrict__ we2P,
    const float* __restrict__ bv, const float* __restrict__ bxo,
    const float* __restrict__ bx1, const float* __restrict__ bx2,
    const float* __restrict__ bem, const float* __restrict__ bea,
    const float* __restrict__ beo, const float* __restrict__ be1,
    const float* __restrict__ be2,
    const float* __restrict__ gnx, const float* __restrict__ bnx,
    const float* __restrict__ gne, const float* __restrict__ bne,
    float* __restrict__ xout, float* __restrict__ eout) {
    __shared__ __align__(16) char ldsbuf[34304];
    const int t = threadIdx.x, wave = t >> 6, lane = t & 63;
    const int quad = lane >> 4, l15 = lane & 15;

    if (blockIdx.x < 64) {
        // ================= x-path remainder (16 rows per block) =============
        short* sXb  = (short*)ldsbuf;              // [16][264] bf16 x
        short* sVb  = (short*)(ldsbuf + 8448);     // [16][264] V bf16
        short* sTbx = (short*)(ldsbuf + 16896);    // [16][264] LN1 out
        short* sRx  = (short*)(ldsbuf + 25344);    // [16][264] newX bf16
        short* sH1x = (short*)(ldsbuf + 25344);    // alias: FF1 quarter
        short* sH2x = (short*)(ldsbuf + 25344);    // alias: FF2 out bf16
        const int m0 = blockIdx.x * 16;

        const float4* x4 = (const float4*)(x + (size_t)m0 * 256);
        for (int g = t; g < 1024; g += 256) {
            float4 v = x4[g];
            int row = g >> 6, col4 = (g & 63) * 4;
            short4v sv = {f2bs(v.x), f2bs(v.y), f2bs(v.z), f2bs(v.w)};
            *(short4v*)(sXb + row * 264 + col4) = sv;
        }
        __syncthreads();

        // V = x @ wv + bv -> sVb bf16 (A-frags cached once)
        {
            short8 aX[8];
#pragma unroll
            for (int kb = 0; kb < 8; ++kb)
                aX[kb] = *(const short8*)(sXb + l15 * 264 + quad * 8 + kb * 32);
#pragma unroll
            for (int ntl = 0; ntl < 4; ++ntl) {
                int nt = wave * 4 + ntl;
                const short* bB = wvP + ((size_t)(nt * 8) * 64 + lane) * 8;
                short8 w[8];
#pragma unroll
                for (int kb = 0; kb < 8; ++kb) w[kb] = *(const short8*)(bB + (size_t)kb * 512);
                f32x4 acc = (f32x4){0.f, 0.f, 0.f, 0.f};
#pragma unroll
                for (int kb = 0; kb < 8; ++kb)
                    acc = __builtin_amdgcn_mfma_f32_16x16x32_bf16(aX[kb], w[kb], acc, 0, 0, 0);
                int col = nt * 16 + l15;
                float bvv = bv[col];
#pragma unroll
                for (int r = 0; r < 4; ++r)
                    sVb[(quad * 4 + r) * 264 + col] = f2bs(acc[r] + bvv);
            }
        }
        __syncthreads();

        // newX = V @ wxo + bxo -> sRx bf16
        {
            short8 aV[8];
#pragma unroll
            for (int kb = 0; kb < 8; ++kb)
                aV[kb] = *(const short8*)(sVb + l15 * 264 + quad * 8 + kb * 32);
#pragma unroll
            for (int ntl = 0; ntl < 4; ++ntl) {
                int nt = wave * 4 + ntl;
                const short* bB = wxoP + ((size_t)(nt * 8) * 64 + lane) * 8;
                short8 w[8];
#pragma unroll
                for (int kb = 0; kb < 8; ++kb) w[kb] = *(const short8*)(bB + (size_t)kb * 512);
                f32x4 acc = (f32x4){0.f, 0.f, 0.f, 0.f};
#pragma unroll
                for (int kb = 0; kb < 8; ++kb)
                    acc = __builtin_amdgcn_mfma_f32_16x16x32_bf16(aV[kb], w[kb], acc, 0, 0, 0);
                int col = nt * 16 + l15;
                float bvv = bxo[col];
#pragma unroll
                for (int r = 0; r < 4; ++r)
                    sRx[(quad * 4 + r) * 264 + col] = f2bs(acc[r] + bvv);
            }
        }
        __syncthreads();

        // LN1 -> sTbx bf16
        for (int rr = 0; rr < 4; ++rr) {
            int row = wave * 4 + rr;
            float v[4];
            float s1 = 0.f, s2 = 0.f;
#pragma unroll
            for (int k = 0; k < 4; ++k) {
                v[k] = bs2f(sXb[row * 264 + lane + 64 * k]) + bs2f(sRx[row * 264 + lane + 64 * k]);
                s1 += v[k]; s2 += v[k] * v[k];
            }
            for (int off = 32; off; off >>= 1) {
                s1 += __shfl_down(s1, off);
                s2 += __shfl_down(s2, off);
            }
            s1 = __shfl(s1, 0); s2 = __shfl(s2, 0);
            float mean = s1 * (1.f / 256.f);
            float var = s2 * (1.f / 256.f) - mean * mean;
            float rstd = rsqrtf(var + 1e-5f);
#pragma unroll
            for (int k = 0; k < 4; ++k)
                sTbx[row * 264 + lane + 64 * k] =
                    f2bs((v[k] - mean) * rstd * gnx[lane + 64 * k] + bnx[lane + 64 * k]);
        }
        __syncthreads();

        // FF in 4 quarters of 256 cols; H2 accumulated in registers.
        short8 aTx[8];
#pragma unroll
        for (int kb = 0; kb < 8; ++kb)
            aTx[kb] = *(const short8*)(sTbx + l15 * 264 + quad * 8 + kb * 32);
        f32x4 accE[4];
#pragma unroll
        for (int p = 0; p < 4; ++p) accE[p] = (f32x4){0.f, 0.f, 0.f, 0.f};

        for (int q = 0; q < 4; ++q) {
            // H1 quarter = relu(T @ wx1[:, q*256:+256] + bx1)
#pragma unroll
            for (int ntl = 0; ntl < 4; ++ntl) {
                int ntg = q * 16 + wave * 4 + ntl;
                const short* bB = wx1P + ((size_t)(ntg * 8) * 64 + lane) * 8;
                short8 w[8];
#pragma unroll
                for (int kb = 0; kb < 8; ++kb) w[kb] = *(const short8*)(bB + (size_t)kb * 512);
                f32x4 acc = (f32x4){0.f, 0.f, 0.f, 0.f};
#pragma unroll
                for (int kb = 0; kb < 8; ++kb)
                    acc = __builtin_amdgcn_mfma_f32_16x16x32_bf16(aTx[kb], w[kb], acc, 0, 0, 0);
                int coll = (wave * 4 + ntl) * 16 + l15;
                float bvv = bx1[ntg * 16 + l15];
#pragma unroll
                for (int r = 0; r < 4; ++r)
                    sH1x[(quad * 4 + r) * 264 + coll] = f2bs(fmaxf(acc[r] + bvv, 0.f));
            }
            __syncthreads();
            // H2 += H1q @ wx2[q*256:+256, :]
            {
                short8 aHx[8];
#pragma unroll
                for (int kb = 0; kb < 8; ++kb)
                    aHx[kb] = *(const short8*)(sH1x + l15 * 264 + quad * 8 + kb * 32);
#pragma unroll
                for (int ntl = 0; ntl < 4; ++ntl) {
                    int nt = wave * 4 + ntl;
                    const short* bB = wx2P + ((size_t)(nt * 32 + q * 8) * 64 + lane) * 8;
                    short8 w[8];
#pragma unroll
                    for (int kb = 0; kb < 8; ++kb) w[kb] = *(const short8*)(bB + (size_t)kb * 512);
#pragma unroll
                    for (int kb = 0; kb < 8; ++kb)
                        accE[ntl] = __builtin_amdgcn_mfma_f32_16x16x32_bf16(aHx[kb], w[kb], accE[ntl], 0, 0, 0);
                }
            }
            __syncthreads();
        }
        // H2 epilogue -> sH2x bf16 (sH1x dead after final barrier)
#pragma unroll
        for (int ntl = 0; ntl < 4; ++ntl) {
            int col = (wave * 4 + ntl) * 16 + l15;
            float bvv = bx2[col];
#pragma unroll
            for (int r = 0; r < 4; ++r)
                sH2x[(quad * 4 + r) * 264 + col] = f2bs(accE[ntl][r] + bvv);
        }
        __syncthreads();

        // LN2 -> xout
        for (int rr = 0; rr < 4; ++rr) {
            int row = wave * 4 + rr;
            float v[4];
            float s1 = 0.f, s2 = 0.f;
#pragma unroll
            for (int k = 0; k < 4; ++k) {
                v[k] = bs2f(sXb[row * 264 + lane + 64 * k]) + bs2f(sH2x[row * 264 + lane + 64 * k]);
                s1 += v[k]; s2 += v[k] * v[k];
            }
            for (int off = 32; off; off >>= 1) {
                s1 += __shfl_down(s1, off);
                s2 += __shfl_down(s2, off);
            }
            s1 = __shfl(s1, 0); s2 = __shfl(s2, 0);
            float mean = s1 * (1.f / 256.f);
            float var = s2 * (1.f / 256.f) - mean * mean;
            float rstd = rsqrtf(var + 1e-5f);
#pragma unroll
            for (int k = 0; k < 4; ++k)
                xout[(size_t)(m0 + row) * 256 + lane + 64 * k] =
                    (v[k] - mean) * rstd * gnx[lane + 64 * k] + bnx[lane + 64 * k];
        }
        return;
    }

    // ==================== e-path (32 rows per block) ========================
    short* sEb = (short*)ldsbuf;               // [32][136] bf16 e
    short* sYb = (short*)(ldsbuf + 8704);      // [32][264] Y bf16
    short* sTb = (short*)(ldsbuf + 8704);      // alias: [32][136] LN1 out
    float* sH2 = (float*)(ldsbuf + 8704);      // alias: [32][132] FF2 out f32
    short* sR  = (short*)(ldsbuf + 25600);     // [32][136] newE bf16
    short* sH1 = (short*)(ldsbuf + 25600);     // alias: [32][136] H1 quarter

    const int r0 = (blockIdx.x - 64) * 32;
    const int b = r0 >> 14;
    const int j0 = r0 & 127;

    float g0 = gne[lane], g1 = gne[lane + 64];
    float bn0 = bne[lane], bn1 = bne[lane + 64];

    // ---- prefetch q*k for this wave's positions (nt = wave*4+ntl, both mt) ----
    float qk[2][4][4];
#pragma unroll
    for (int ntl = 0; ntl < 4; ++ntl) {
        const int col = (wave * 4 + ntl) * 16 + l15;
        const float q = Qb[(size_t)(r0 >> 7) * 256 + col] * RSQRT_DF;
#pragma unroll
        for (int mt = 0; mt < 2; ++mt) {
            const float* kp = Kb + (size_t)((b << 7) + j0 + mt * 16 + quad * 4) * 256 + col;
#pragma unroll
            for (int r = 0; r < 4; ++r) qk[mt][ntl][r] = q * kp[(size_t)r * 256];
        }
    }

    // ---- load e tile (bf16) ----
    {
        const float4* e4 = (const float4*)(e + (size_t)r0 * 128);
        for (int g = t; g < 1024; g += 256) {
            float4 v = e4[g];
            int row = g >> 5, col4 = (g & 31) * 4;
            short4v sv = {f2bs(v.x), f2bs(v.y), f2bs(v.z), f2bs(v.w)};
            *(short4v*)(sEb + row * 136 + col4) = sv;
        }
    }
    __syncthreads();

    // ---- Stage B: E1/E2 MFMA; Y = qk*(E1+1)+E2 -> sYb ----
    {
        short8 aE[2][4];
#pragma unroll
        for (int mt = 0; mt < 2; ++mt)
#pragma unroll
            for (int kb = 0; kb < 4; ++kb)
                aE[mt][kb] = *(const short8*)(sEb + (mt * 16 + l15) * 136 + quad * 8 + kb * 32);
#pragma unroll
        for (int ntl = 0; ntl < 4; ++ntl) {
            const int nt = wave * 4 + ntl;
            const short* b1 = wemP + ((size_t)(nt * 4) * 64 + lane) * 8;
            const short* b2 = weaP + ((size_t)(nt * 4) * 64 + lane) * 8;
            short8 w1[4], w2[4];
#pragma unroll
            for (int kb = 0; kb < 4; ++kb) {
                w1[kb] = *(const short8*)(b1 + (size_t)kb * 512);
                w2[kb] = *(const short8*)(b2 + (size_t)kb * 512);
            }
            const int col = nt * 16 + l15;
            const float bm = bem[col], ba = bea[col];
#pragma unroll
            for (int mt = 0; mt < 2; ++mt) {
                f32x4 a1 = (f32x4){0.f, 0.f, 0.f, 0.f};
                f32x4 a2 = (f32x4){0.f, 0.f, 0.f, 0.f};
#pragma unroll
                for (int kb = 0; kb < 4; ++kb) {
                    a1 = __builtin_amdgcn_mfma_f32_16x16x32_bf16(aE[mt][kb], w1[kb], a1, 0, 0, 0);
                    a2 = __builtin_amdgcn_mfma_f32_16x16x32_bf16(aE[mt][kb], w2[kb], a2, 0, 0, 0);
                }
#pragma unroll
                for (int r = 0; r < 4; ++r) {
                    int row = mt * 16 + quad * 4 + r;
                    float y = qk[mt][ntl][r] * (a1[r] + bm + 1.0f) + (a2[r] + ba);
                    sYb[row * 264 + col] = f2bs(y);
                }
            }
        }
    }
    __syncthreads();

    // ---- Stage C: newE = Y @ weo + beo -> sR bf16 ----
    {
        short8 aY[2][8];
#pragma unroll
        for (int mt = 0; mt < 2; ++mt)
#pragma unroll
            for (int kb = 0; kb < 8; ++kb)
                aY[mt][kb] = *(const short8*)(sYb + (mt * 16 + l15) * 264 + quad * 8 + kb * 32);
#pragma unroll
        for (int ntl = 0; ntl < 2; ++ntl) {
            const int nt = wave * 2 + ntl;
            const short* bB = weoP + ((size_t)(nt * 8) * 64 + lane) * 8;
            short8 w[8];
#pragma unroll
            for (int kb = 0; kb < 8; ++kb) w[kb] = *(const short8*)(bB + (size_t)kb * 512);
            const int col = nt * 16 + l15;
            const float bo = beo[col];
#pragma unroll
            for (int mt = 0; mt < 2; ++mt) {
                f32x4 acc = (f32x4){0.f, 0.f, 0.f, 0.f};
#pragma unroll
                for (int kb = 0; kb < 8; ++kb)
                    acc = __builtin_amdgcn_mfma_f32_16x16x32_bf16(aY[mt][kb], w[kb], acc, 0, 0, 0);
#pragma unroll
                for (int r = 0; r < 4; ++r)
                    sR[(mt * 16 + quad * 4 + r) * 136 + col] = f2bs(acc[r] + bo);
            }
        }
    }
    __syncthreads();

    // ---- LN1: sTb = bf16(LN(e + newE)*gne + bne)  (sTb aliases dead sYb) ----
    for (int rr = 0; rr < 8; ++rr) {
        int row = wave * 8 + rr;
        float v0 = bs2f(sEb[row * 136 + lane]) + bs2f(sR[row * 136 + lane]);
        float v1 = bs2f(sEb[row * 136 + lane + 64]) + bs2f(sR[row * 136 + lane + 64]);
        float s1 = v0 + v1, s2 = v0 * v0 + v1 * v1;
        for (int off = 32; off; off >>= 1) {
            s1 += __shfl_down(s1, off);
            s2 += __shfl_down(s2, off);
        }
        s1 = __shfl(s1, 0); s2 = __shfl(s2, 0);
        float mean = s1 * 0.0078125f;
        float var = s2 * 0.0078125f - mean * mean;
        float rstd = rsqrtf(var + 1e-5f);
        sTb[row * 136 + lane]      = f2bs((v0 - mean) * rstd * g0 + bn0);
        sTb[row * 136 + lane + 64] = f2bs((v1 - mean) * rstd * g1 + bn1);
    }
    __syncthreads();

    // ---- FF in 4 quarters of 128 cols; H2 accumulated in registers ----
    short8 aT[2][4];
#pragma unroll
    for (int mt = 0; mt < 2; ++mt)
#pragma unroll
        for (int kb = 0; kb < 4; ++kb)
            aT[mt][kb] = *(const short8*)(sTb + (mt * 16 + l15) * 136 + quad * 8 + kb * 32);
    f32x4 accE[4];
#pragma unroll
    for (int p = 0; p < 4; ++p) accE[p] = (f32x4){0.f, 0.f, 0.f, 0.f};

    for (int q = 0; q < 4; ++q) {
        // H1q = relu(T @ we1[:, q*128:+128] + be1)
#pragma unroll
        for (int ntl = 0; ntl < 2; ++ntl) {
            const int ntg = q * 8 + wave * 2 + ntl;
            const short* bB = we1P + ((size_t)(ntg * 4) * 64 + lane) * 8;
            short8 w[4];
#pragma unroll
            for (int kb = 0; kb < 4; ++kb) w[kb] = *(const short8*)(bB + (size_t)kb * 512);
            const int coll = (wave * 2 + ntl) * 16 + l15;
            const float bvv = be1[ntg * 16 + l15];
#pragma unroll
            for (int mt = 0; mt < 2; ++mt) {
                f32x4 acc = (f32x4){0.f, 0.f, 0.f, 0.f};
#pragma unroll
                for (int kb = 0; kb < 4; ++kb)
                    acc = __builtin_amdgcn_mfma_f32_16x16x32_bf16(aT[mt][kb], w[kb], acc, 0, 0, 0);
#pragma unroll
                for (int r = 0; r < 4; ++r)
                    sH1[(mt * 16 + quad * 4 + r) * 136 + coll] = f2bs(fmaxf(acc[r] + bvv, 0.f));
            }
        }
        __syncthreads();
        // H2 += H1q @ we2[q*128:+128, :]
        {
            short8 aH[2][4];
#pragma unroll
            for (int mt = 0; mt < 2; ++mt)
#pragma unroll
                for (int kb = 0; kb < 4; ++kb)
                    aH[mt][kb] = *(const short8*)(sH1 + (mt * 16 + l15) * 136 + quad * 8 + kb * 32);
#pragma unroll
            for (int ntl = 0; ntl < 2; ++ntl) {
                const int nt = wave * 2 + ntl;
                const short* bB = we2P + ((size_t)(nt * 16 + q * 4) * 64 + lane) * 8;
                short8 w[4];
#pragma unroll
                for (int kb = 0; kb < 4; ++kb) w[kb] = *(const short8*)(bB + (size_t)kb * 512);
#pragma unroll
                for (int mt = 0; mt < 2; ++mt) {
#pragma unroll
                    for (int kb = 0; kb < 4; ++kb)
                        accE[ntl * 2 + mt] = __builtin_amdgcn_mfma_f32_16x16x32_bf16(
                            aH[mt][kb], w[kb], accE[ntl * 2 + mt], 0, 0, 0);
                }
            }
        }
        __syncthreads();
    }
    // epilogue -> sH2 f32 (over dead sTb/sYb region)
#pragma unroll
    for (int ntl = 0; ntl < 2; ++ntl)
#pragma unroll
        for (int mt = 0; mt < 2; ++mt) {
            const int col = (wave * 2 + ntl) * 16 + l15;
            const float bvv = be2[col];
#pragma unroll
            for (int r = 0; r < 4; ++r)
                sH2[(mt * 16 + quad * 4 + r) * 132 + col] = accE[ntl * 2 + mt][r] + bvv;
        }
    __syncthreads();

    // ---- LN2 -> global ----
    for (int rr = 0; rr < 8; ++rr) {
        int row = wave * 8 + rr;
        float v0 = bs2f(sEb[row * 136 + lane]) + sH2[row * 132 + lane];
        float v1 = bs2f(sEb[row * 136 + lane + 64]) + sH2[row * 132 + lane + 64];
        float s1 = v0 + v1, s2 = v0 * v0 + v1 * v1;
        for (int off = 32; off; off >>= 1) {
            s1 += __shfl_down(s1, off);
            s2 += __shfl_down(s2, off);
        }
        s1 = __shfl(s1, 0); s2 = __shfl(s2, 0);
        float mean = s1 * 0.0078125f;
        float var = s2 * 0.0078125f - mean * mean;
        float rstd = rsqrtf(var + 1e-5f);
        size_t o = (size_t)(r0 + row) * 128;
        eout[o + lane]      = (v0 - mean) * rstd * g0 + bn0;
        eout[o + lane + 64] = (v1 - mean) * rstd * g1 + bn1;
    }
}

extern "C" void kernel_launch(void* const* d_in, const int* in_sizes, int n_in,
                              void* d_out, int out_size, void* d_ws, size_t ws_size,
                              hipStream_t stream) {
    const float* x   = (const float*)d_in[0];
    const float* e   = (const float*)d_in[1];
    const float* wq  = (const float*)d_in[2];
    const float* wk  = (const float*)d_in[3];
    const float* wv  = (const float*)d_in[4];
    const float* wem = (const float*)d_in[5];
    const float* wea = (const float*)d_in[6];
    const float* wxo = (const float*)d_in[7];
    const float* weo = (const float*)d_in[8];
    const float* wx1 = (const float*)d_in[9];
    const float* wx2 = (const float*)d_in[10];
    const float* we1 = (const float*)d_in[11];
    const float* we2 = (const float*)d_in[12];
    const float* bq  = (const float*)d_in[13];
    const float* bk  = (const float*)d_in[14];
    const float* bv  = (const float*)d_in[15];
    const float* bem = (const float*)d_in[16];
    const float* bea = (const float*)d_in[17];
    const float* bxo = (const float*)d_in[18];
    const float* beo = (const float*)d_in[19];
    const float* bx1 = (const float*)d_in[20];
    const float* bx2 = (const float*)d_in[21];
    const float* be1 = (const float*)d_in[22];
    const float* be2 = (const float*)d_in[23];
    const float* gnx = (const float*)d_in[24];
    const float* bnx = (const float*)d_in[25];
    const float* gne = (const float*)d_in[26];
    const float* bne = (const float*)d_in[27];

    float* out = (float*)d_out;  // x_out (262144) then e_out (16777216)

    float* ws = (float*)d_ws;
    float* Qb = ws;               // 262144 f32
    float* Kb = Qb + 262144;      // 262144 f32
    short* base = (short*)(Kb + 262144);
    short* wqP  = base;           // 65536
    short* wkP  = wqP + 65536;
    short* wvP  = wkP + 65536;
    short* wxoP = wvP + 65536;
    short* wx1P = wxoP + 65536;   // 262144
    short* wx2P = wx1P + 262144;  // 262144
    short* wemP = wx2P + 262144;  // 32768
    short* weaP = wemP + 32768;
    short* weoP = weaP + 32768;
    short* we1P = weoP + 32768;   // 65536
    short* we2P = we1P + 65536;   // 65536

    // ---- one pack launch for all 11 weights ----
    PackArgs pa;
    const float* Ws[11] = {wq, wk, wv, wxo, wx1, wx2, wem, wea, weo, we1, we2};
    short* Wps[11] = {wqP, wkP, wvP, wxoP, wx1P, wx2P, wemP, weaP, weoP, we1P, we2P};
    int Ks[11] = {256, 256, 256, 256, 256, 1024, 128, 128, 256, 128, 512};
    int Ns[11] = {256, 256, 256, 256, 1024, 256, 256, 256, 128, 512, 128};
    int acc = 0;
    for (int i = 0; i < 11; ++i) {
        pa.W[i] = Ws[i];
        pa.Wp[i] = Wps[i];
        pa.kdiv[i] = Ks[i] >> 5;
        pa.N[i] = Ns[i];
        pa.start[i] = acc;
        acc += (Ns[i] >> 4) * (Ks[i] >> 5) * 64;
    }
    pa.start[11] = acc;
    pack_all<<<(acc + 255) / 256, 256, 0, stream>>>(pa);

    // ---- Q/K GEMM (only cross-path dependency) ----
    qk_gemm<<<128, 256, 0, stream>>>(x, wqP, wkP, bq, bk, Qb, Kb);

    // ---- fused main: 64 x-rest blocks (first, overlap) + 4096 e-path ----
    fused_main<<<4160, 256, 0, stream>>>(
        x, e, Qb, Kb, wvP, wxoP, wx1P, wx2P, wemP, weaP, weoP, we1P, we2P,
        bv, bxo, bx1, bx2, bem, bea, beo, be1, be2,
        gnx, bnx, gne, bne, out, out + 262144);
}

// Round 3
// 283.481 us; speedup vs baseline: 1.2538x; 1.2538x over previous
//
#include <hip/hip_runtime.h>

// ---------------------------------------------------------------------------
// B=8, N=128, XD=256, ED=128, H=8, DF=32, FFX=1024, FFE=512. All I/O fp32.
// softmax over axis=1 + (attn*V).sum(1) collapses to V => newX = (x@wv+bv)@wxo+bxo.
// bf16 MFMA 16x16x32, fp32 accumulate. Verified layouts:
//   A-frag: lane holds A[m=lane&15][k=(lane>>4)*8 + j], j=0..7
//   B-frag: lane holds B[k=(lane>>4)*8+j][n=lane&15]  (pre-packed contiguous)
//   C/D   : col=lane&15, row=(lane>>4)*4 + reg
// Round 7: register-blocked e-path (weights loaded once per wave; A-frags
// cached across nt).
// Round 8: LDS 51200->34304 (FF quarters, liveness aliasing, bf16 residuals)
// -> 4 blocks/CU. REGRESSED: __launch_bounds__(256,4) made the allocator
// clamp to 64 VGPRs (8-wave target) and spill the register-blocking to
// scratch: WRITE_SIZE 66->229 MB, FETCH 44->118 MB, dur 167->217 us.
// Round 9: revert bound to (256,3) — cap ~170, natural allocation ~80-110,
// no spills; LDS still permits 4 blocks/CU. Occupancy gain + reg-blocking
// now stack. // block=256: (256,3) known-good (R1: 76 VGPR, no spill);
// (256,4) clamps to 64 VGPR + scratch spills — do not use.
// ---------------------------------------------------------------------------

#define RSQRT_DF 0.17677669529663687f  // 1/sqrt(32)

typedef __attribute__((ext_vector_type(8))) short short8;
typedef __attribute__((ext_vector_type(4))) short short4v;
typedef __attribute__((ext_vector_type(4))) float f32x4;

__device__ __forceinline__ short f2bs(float f) {  // fp32->bf16 bits, RNE
    unsigned u = __float_as_uint(f);
    unsigned r = u + 0x7FFFu + ((u >> 16) & 1u);
    return (short)(r >> 16);
}
__device__ __forceinline__ float bs2f(short s) {  // bf16 bits->fp32
    return __uint_as_float(((unsigned)(unsigned short)s) << 16);
}

// ---------------- single-launch weight pack (all 11 weights) ----------------
struct PackArgs {
    const float* W[11];
    short* Wp[11];
    int kdiv[11];   // K/32
    int N[11];
    int start[12];  // prefix sums of per-weight group counts; start[11]=total
};

__global__ __launch_bounds__(256) void pack_all(PackArgs pa) {
    int g = blockIdx.x * 256 + threadIdx.x;
    if (g >= pa.start[11]) return;
    int i = 0;
    while (g >= pa.start[i + 1]) ++i;
    int local = g - pa.start[i];
    int kdiv = pa.kdiv[i], N = pa.N[i];
    int lane = local & 63, rest = local >> 6;
    int kb = rest % kdiv, nt = rest / kdiv;
    int n = nt * 16 + (lane & 15);
    int k0 = kb * 32 + ((lane >> 4) << 3);
    const float* W = pa.W[i];
    short8 v;
#pragma unroll
    for (int j = 0; j < 8; ++j) v[j] = f2bs(W[(size_t)(k0 + j) * N + n]);
    *(short8*)(pa.Wp[i] + (size_t)local * 8) = v;
}

// ---------------- Q/K GEMM (feeds e-path) ----------------------------------
__global__ __launch_bounds__(256) void qk_gemm(
    const float* __restrict__ x,
    const short* __restrict__ wqP, const short* __restrict__ wkP,
    const float* __restrict__ bq, const float* __restrict__ bk,
    float* __restrict__ Qb, float* __restrict__ Kb) {
    __shared__ short sXb[16 * 264];
    const int t = threadIdx.x, wave = t >> 6, lane = t & 63;
    const int quad = lane >> 4, l15 = lane & 15;
    const int m0 = (blockIdx.x & 63) * 16;
    const int isK = blockIdx.x >> 6;
    const short* wP = isK ? wkP : wqP;
    const float* bp = isK ? bk : bq;
    float* outp = isK ? Kb : Qb;

    const float4* x4 = (const float4*)(x + (size_t)m0 * 256);
    for (int g = t; g < 1024; g += 256) {
        float4 v = x4[g];
        int row = g >> 6, col4 = (g & 63) * 4;
        short4v sv = {f2bs(v.x), f2bs(v.y), f2bs(v.z), f2bs(v.w)};
        *(short4v*)(sXb + row * 264 + col4) = sv;
    }
    __syncthreads();

#pragma unroll 2
    for (int p = 0; p < 4; ++p) {
        int nt = wave * 4 + p;
        f32x4 acc = (f32x4){0.f, 0.f, 0.f, 0.f};
        const short* aB = sXb + l15 * 264 + quad * 8;
        const short* bB = wP + ((size_t)(nt * 8) * 64 + lane) * 8;
#pragma unroll
        for (int kb = 0; kb < 8; ++kb) {
            short8 a = *(const short8*)(aB + kb * 32);
            short8 w = *(const short8*)(bB + (size_t)kb * 512);
            acc = __builtin_amdgcn_mfma_f32_16x16x32_bf16(a, w, acc, 0, 0, 0);
        }
        int col = nt * 16 + l15;
        float bvv = bp[col];
#pragma unroll
        for (int r = 0; r < 4; ++r)
            outp[(size_t)(m0 + quad * 4 + r) * 256 + col] = acc[r] + bvv;
    }
}

// ---------------- fused main: 64 x-rest blocks + 4096 e-path blocks --------
// LDS 34304 B -> 4 blocks/CU (137216 <= 163840) provided VGPR <= 128.
// e-path: sEb@0 [32][136] 8704 | R3@8704 16896: sYb[32][264] -> sTb[32][136]
//         -> sH2 f32 [32][132] | R2@25600 8704: sR[32][136] bf16 -> sH1[32][136]
// x-path: sXb@0 8448 | sVb@8448 8448 | sTbx@16896 8448 |
//         R@25344 8448: sRx bf16 -> sH1x quarter -> sH2x bf16   (33792 total)
__global__ __launch_bounds__(256, 3) void fused_main(
    const float* __restrict__ x, const float* __restrict__ e,
    const float* __restrict__ Qb, const float* __restrict__ Kb,
    const short* __restrict__ wvP, const short* __restrict__ wxoP,
    const short* __restrict__ wx1P, const short* __restrict__ wx2P,
    const short* __restrict__ wemP, const short* __restrict__ weaP,
    const short* __restrict__ weoP, const short* __restrict__ we1P,
    const short* __restrict__ we2P,
    const float* __restrict__ bv, const float* __restrict__ bxo,
    const float* __restrict__ bx1, const float* __restrict__ bx2,
    const float* __restrict__ bem, const float* __restrict__ bea,
    const float* __restrict__ beo, const float* __restrict__ be1,
    const float* __restrict__ be2,
    const float* __restrict__ gnx, const float* __restrict__ bnx,
    const float* __restrict__ gne, const float* __restrict__ bne,
    float* __restrict__ xout, float* __restrict__ eout) {
    __shared__ __align__(16) char ldsbuf[34304];
    const int t = threadIdx.x, wave = t >> 6, lane = t & 63;
    const int quad = lane >> 4, l15 = lane & 15;

    if (blockIdx.x < 64) {
        // ================= x-path remainder (16 rows per block) =============
        short* sXb  = (short*)ldsbuf;              // [16][264] bf16 x
        short* sVb  = (short*)(ldsbuf + 8448);     // [16][264] V bf16
        short* sTbx = (short*)(ldsbuf + 16896);    // [16][264] LN1 out
        short* sRx  = (short*)(ldsbuf + 25344);    // [16][264] newX bf16
        short* sH1x = (short*)(ldsbuf + 25344);    // alias: FF1 quarter
        short* sH2x = (short*)(ldsbuf + 25344);    // alias: FF2 out bf16
        const int m0 = blockIdx.x * 16;

        const float4* x4 = (const float4*)(x + (size_t)m0 * 256);
        for (int g = t; g < 1024; g += 256) {
            float4 v = x4[g];
            int row = g >> 6, col4 = (g & 63) * 4;
            short4v sv = {f2bs(v.x), f2bs(v.y), f2bs(v.z), f2bs(v.w)};
            *(short4v*)(sXb + row * 264 + col4) = sv;
        }
        __syncthreads();

        // V = x @ wv + bv -> sVb bf16 (A-frags cached once)
        {
            short8 aX[8];
#pragma unroll
            for (int kb = 0; kb < 8; ++kb)
                aX[kb] = *(const short8*)(sXb + l15 * 264 + quad * 8 + kb * 32);
#pragma unroll
            for (int ntl = 0; ntl < 4; ++ntl) {
                int nt = wave * 4 + ntl;
                const short* bB = wvP + ((size_t)(nt * 8) * 64 + lane) * 8;
                short8 w[8];
#pragma unroll
                for (int kb = 0; kb < 8; ++kb) w[kb] = *(const short8*)(bB + (size_t)kb * 512);
                f32x4 acc = (f32x4){0.f, 0.f, 0.f, 0.f};
#pragma unroll
                for (int kb = 0; kb < 8; ++kb)
                    acc = __builtin_amdgcn_mfma_f32_16x16x32_bf16(aX[kb], w[kb], acc, 0, 0, 0);
                int col = nt * 16 + l15;
                float bvv = bv[col];
#pragma unroll
                for (int r = 0; r < 4; ++r)
                    sVb[(quad * 4 + r) * 264 + col] = f2bs(acc[r] + bvv);
            }
        }
        __syncthreads();

        // newX = V @ wxo + bxo -> sRx bf16
        {
            short8 aV[8];
#pragma unroll
            for (int kb = 0; kb < 8; ++kb)
                aV[kb] = *(const short8*)(sVb + l15 * 264 + quad * 8 + kb * 32);
#pragma unroll
            for (int ntl = 0; ntl < 4; ++ntl) {
                int nt = wave * 4 + ntl;
                const short* bB = wxoP + ((size_t)(nt * 8) * 64 + lane) * 8;
                short8 w[8];
#pragma unroll
                for (int kb = 0; kb < 8; ++kb) w[kb] = *(const short8*)(bB + (size_t)kb * 512);
                f32x4 acc = (f32x4){0.f, 0.f, 0.f, 0.f};
#pragma unroll
                for (int kb = 0; kb < 8; ++kb)
                    acc = __builtin_amdgcn_mfma_f32_16x16x32_bf16(aV[kb], w[kb], acc, 0, 0, 0);
                int col = nt * 16 + l15;
                float bvv = bxo[col];
#pragma unroll
                for (int r = 0; r < 4; ++r)
                    sRx[(quad * 4 + r) * 264 + col] = f2bs(acc[r] + bvv);
            }
        }
        __syncthreads();

        // LN1 -> sTbx bf16
        for (int rr = 0; rr < 4; ++rr) {
            int row = wave * 4 + rr;
            float v[4];
            float s1 = 0.f, s2 = 0.f;
#pragma unroll
            for (int k = 0; k < 4; ++k) {
                v[k] = bs2f(sXb[row * 264 + lane + 64 * k]) + bs2f(sRx[row * 264 + lane + 64 * k]);
                s1 += v[k]; s2 += v[k] * v[k];
            }
            for (int off = 32; off; off >>= 1) {
                s1 += __shfl_down(s1, off);
                s2 += __shfl_down(s2, off);
            }
            s1 = __shfl(s1, 0); s2 = __shfl(s2, 0);
            float mean = s1 * (1.f / 256.f);
            float var = s2 * (1.f / 256.f) - mean * mean;
            float rstd = rsqrtf(var + 1e-5f);
#pragma unroll
            for (int k = 0; k < 4; ++k)
                sTbx[row * 264 + lane + 64 * k] =
                    f2bs((v[k] - mean) * rstd * gnx[lane + 64 * k] + bnx[lane + 64 * k]);
        }
        __syncthreads();

        // FF in 4 quarters of 256 cols; H2 accumulated in registers.
        short8 aTx[8];
#pragma unroll
        for (int kb = 0; kb < 8; ++kb)
            aTx[kb] = *(const short8*)(sTbx + l15 * 264 + quad * 8 + kb * 32);
        f32x4 accE[4];
#pragma unroll
        for (int p = 0; p < 4; ++p) accE[p] = (f32x4){0.f, 0.f, 0.f, 0.f};

        for (int q = 0; q < 4; ++q) {
            // H1 quarter = relu(T @ wx1[:, q*256:+256] + bx1)
#pragma unroll
            for (int ntl = 0; ntl < 4; ++ntl) {
                int ntg = q * 16 + wave * 4 + ntl;
                const short* bB = wx1P + ((size_t)(ntg * 8) * 64 + lane) * 8;
                short8 w[8];
#pragma unroll
                for (int kb = 0; kb < 8; ++kb) w[kb] = *(const short8*)(bB + (size_t)kb * 512);
                f32x4 acc = (f32x4){0.f, 0.f, 0.f, 0.f};
#pragma unroll
                for (int kb = 0; kb < 8; ++kb)
                    acc = __builtin_amdgcn_mfma_f32_16x16x32_bf16(aTx[kb], w[kb], acc, 0, 0, 0);
                int coll = (wave * 4 + ntl) * 16 + l15;
                float bvv = bx1[ntg * 16 + l15];
#pragma unroll
                for (int r = 0; r < 4; ++r)
                    sH1x[(quad * 4 + r) * 264 + coll] = f2bs(fmaxf(acc[r] + bvv, 0.f));
            }
            __syncthreads();
            // H2 += H1q @ wx2[q*256:+256, :]
            {
                short8 aHx[8];
#pragma unroll
                for (int kb = 0; kb < 8; ++kb)
                    aHx[kb] = *(const short8*)(sH1x + l15 * 264 + quad * 8 + kb * 32);
#pragma unroll
                for (int ntl = 0; ntl < 4; ++ntl) {
                    int nt = wave * 4 + ntl;
                    const short* bB = wx2P + ((size_t)(nt * 32 + q * 8) * 64 + lane) * 8;
                    short8 w[8];
#pragma unroll
                    for (int kb = 0; kb < 8; ++kb) w[kb] = *(const short8*)(bB + (size_t)kb * 512);
#pragma unroll
                    for (int kb = 0; kb < 8; ++kb)
                        accE[ntl] = __builtin_amdgcn_mfma_f32_16x16x32_bf16(aHx[kb], w[kb], accE[ntl], 0, 0, 0);
                }
            }
            __syncthreads();
        }
        // H2 epilogue -> sH2x bf16 (sH1x dead after final barrier)
#pragma unroll
        for (int ntl = 0; ntl < 4; ++ntl) {
            int col = (wave * 4 + ntl) * 16 + l15;
            float bvv = bx2[col];
#pragma unroll
            for (int r = 0; r < 4; ++r)
                sH2x[(quad * 4 + r) * 264 + col] = f2bs(accE[ntl][r] + bvv);
        }
        __syncthreads();

        // LN2 -> xout
        for (int rr = 0; rr < 4; ++rr) {
            int row = wave * 4 + rr;
            float v[4];
            float s1 = 0.f, s2 = 0.f;
#pragma unroll
            for (int k = 0; k < 4; ++k) {
                v[k] = bs2f(sXb[row * 264 + lane + 64 * k]) + bs2f(sH2x[row * 264 + lane + 64 * k]);
                s1 += v[k]; s2 += v[k] * v[k];
            }
            for (int off = 32; off; off >>= 1) {
                s1 += __shfl_down(s1, off);
                s2 += __shfl_down(s2, off);
            }
            s1 = __shfl(s1, 0); s2 = __shfl(s2, 0);
            float mean = s1 * (1.f / 256.f);
            float var = s2 * (1.f / 256.f) - mean * mean;
            float rstd = rsqrtf(var + 1e-5f);
#pragma unroll
            for (int k = 0; k < 4; ++k)
                xout[(size_t)(m0 + row) * 256 + lane + 64 * k] =
                    (v[k] - mean) * rstd * gnx[lane + 64 * k] + bnx[lane + 64 * k];
        }
        return;
    }

    // ==================== e-path (32 rows per block) ========================
    short* sEb = (short*)ldsbuf;               // [32][136] bf16 e
    short* sYb = (short*)(ldsbuf + 8704);      // [32][264] Y bf16
    short* sTb = (short*)(ldsbuf + 8704);      // alias: [32][136] LN1 out
    float* sH2 = (float*)(ldsbuf + 8704);      // alias: [32][132] FF2 out f32
    short* sR  = (short*)(ldsbuf + 25600);     // [32][136] newE bf16
    short* sH1 = (short*)(ldsbuf + 25600);     // alias: [32][136] H1 quarter

    const int r0 = (blockIdx.x - 64) * 32;
    const int b = r0 >> 14;
    const int j0 = r0 & 127;

    float g0 = gne[lane], g1 = gne[lane + 64];
    float bn0 = bne[lane], bn1 = bne[lane + 64];

    // ---- prefetch q*k for this wave's positions (nt = wave*4+ntl, both mt) ----
    float qk[2][4][4];
#pragma unroll
    for (int ntl = 0; ntl < 4; ++ntl) {
        const int col = (wave * 4 + ntl) * 16 + l15;
        const float q = Qb[(size_t)(r0 >> 7) * 256 + col] * RSQRT_DF;
#pragma unroll
        for (int mt = 0; mt < 2; ++mt) {
            const float* kp = Kb + (size_t)((b << 7) + j0 + mt * 16 + quad * 4) * 256 + col;
#pragma unroll
            for (int r = 0; r < 4; ++r) qk[mt][ntl][r] = q * kp[(size_t)r * 256];
        }
    }

    // ---- load e tile (bf16) ----
    {
        const float4* e4 = (const float4*)(e + (size_t)r0 * 128);
        for (int g = t; g < 1024; g += 256) {
            float4 v = e4[g];
            int row = g >> 5, col4 = (g & 31) * 4;
            short4v sv = {f2bs(v.x), f2bs(v.y), f2bs(v.z), f2bs(v.w)};
            *(short4v*)(sEb + row * 136 + col4) = sv;
        }
    }
    __syncthreads();

    // ---- Stage B: E1/E2 MFMA; Y = qk*(E1+1)+E2 -> sYb ----
    {
        short8 aE[2][4];
#pragma unroll
        for (int mt = 0; mt < 2; ++mt)
#pragma unroll
            for (int kb = 0; kb < 4; ++kb)
                aE[mt][kb] = *(const short8*)(sEb + (mt * 16 + l15) * 136 + quad * 8 + kb * 32);
#pragma unroll
        for (int ntl = 0; ntl < 4; ++ntl) {
            const int nt = wave * 4 + ntl;
            const short* b1 = wemP + ((size_t)(nt * 4) * 64 + lane) * 8;
            const short* b2 = weaP + ((size_t)(nt * 4) * 64 + lane) * 8;
            short8 w1[4], w2[4];
#pragma unroll
            for (int kb = 0; kb < 4; ++kb) {
                w1[kb] = *(const short8*)(b1 + (size_t)kb * 512);
                w2[kb] = *(const short8*)(b2 + (size_t)kb * 512);
            }
            const int col = nt * 16 + l15;
            const float bm = bem[col], ba = bea[col];
#pragma unroll
            for (int mt = 0; mt < 2; ++mt) {
                f32x4 a1 = (f32x4){0.f, 0.f, 0.f, 0.f};
                f32x4 a2 = (f32x4){0.f, 0.f, 0.f, 0.f};
#pragma unroll
                for (int kb = 0; kb < 4; ++kb) {
                    a1 = __builtin_amdgcn_mfma_f32_16x16x32_bf16(aE[mt][kb], w1[kb], a1, 0, 0, 0);
                    a2 = __builtin_amdgcn_mfma_f32_16x16x32_bf16(aE[mt][kb], w2[kb], a2, 0, 0, 0);
                }
#pragma unroll
                for (int r = 0; r < 4; ++r) {
                    int row = mt * 16 + quad * 4 + r;
                    float y = qk[mt][ntl][r] * (a1[r] + bm + 1.0f) + (a2[r] + ba);
                    sYb[row * 264 + col] = f2bs(y);
                }
            }
        }
    }
    __syncthreads();

    // ---- Stage C: newE = Y @ weo + beo -> sR bf16 ----
    {
        short8 aY[2][8];
#pragma unroll
        for (int mt = 0; mt < 2; ++mt)
#pragma unroll
            for (int kb = 0; kb < 8; ++kb)
                aY[mt][kb] = *(const short8*)(sYb + (mt * 16 + l15) * 264 + quad * 8 + kb * 32);
#pragma unroll
        for (int ntl = 0; ntl < 2; ++ntl) {
            const int nt = wave * 2 + ntl;
            const short* bB = weoP + ((size_t)(nt * 8) * 64 + lane) * 8;
            short8 w[8];
#pragma unroll
            for (int kb = 0; kb < 8; ++kb) w[kb] = *(const short8*)(bB + (size_t)kb * 512);
            const int col = nt * 16 + l15;
            const float bo = beo[col];
#pragma unroll
            for (int mt = 0; mt < 2; ++mt) {
                f32x4 acc = (f32x4){0.f, 0.f, 0.f, 0.f};
#pragma unroll
                for (int kb = 0; kb < 8; ++kb)
                    acc = __builtin_amdgcn_mfma_f32_16x16x32_bf16(aY[mt][kb], w[kb], acc, 0, 0, 0);
#pragma unroll
                for (int r = 0; r < 4; ++r)
                    sR[(mt * 16 + quad * 4 + r) * 136 + col] = f2bs(acc[r] + bo);
            }
        }
    }
    __syncthreads();

    // ---- LN1: sTb = bf16(LN(e + newE)*gne + bne)  (sTb aliases dead sYb) ----
    for (int rr = 0; rr < 8; ++rr) {
        int row = wave * 8 + rr;
        float v0 = bs2f(sEb[row * 136 + lane]) + bs2f(sR[row * 136 + lane]);
        float v1 = bs2f(sEb[row * 136 + lane + 64]) + bs2f(sR[row * 136 + lane + 64]);
        float s1 = v0 + v1, s2 = v0 * v0 + v1 * v1;
        for (int off = 32; off; off >>= 1) {
            s1 += __shfl_down(s1, off);
            s2 += __shfl_down(s2, off);
        }
        s1 = __shfl(s1, 0); s2 = __shfl(s2, 0);
        float mean = s1 * 0.0078125f;
        float var = s2 * 0.0078125f - mean * mean;
        float rstd = rsqrtf(var + 1e-5f);
        sTb[row * 136 + lane]      = f2bs((v0 - mean) * rstd * g0 + bn0);
        sTb[row * 136 + lane + 64] = f2bs((v1 - mean) * rstd * g1 + bn1);
    }
    __syncthreads();

    // ---- FF in 4 quarters of 128 cols; H2 accumulated in registers ----
    short8 aT[2][4];
#pragma unroll
    for (int mt = 0; mt < 2; ++mt)
#pragma unroll
        for (int kb = 0; kb < 4; ++kb)
            aT[mt][kb] = *(const short8*)(sTb + (mt * 16 + l15) * 136 + quad * 8 + kb * 32);
    f32x4 accE[4];
#pragma unroll
    for (int p = 0; p < 4; ++p) accE[p] = (f32x4){0.f, 0.f, 0.f, 0.f};

    for (int q = 0; q < 4; ++q) {
        // H1q = relu(T @ we1[:, q*128:+128] + be1)
#pragma unroll
        for (int ntl = 0; ntl < 2; ++ntl) {
            const int ntg = q * 8 + wave * 2 + ntl;
            const short* bB = we1P + ((size_t)(ntg * 4) * 64 + lane) * 8;
            short8 w[4];
#pragma unroll
            for (int kb = 0; kb < 4; ++kb) w[kb] = *(const short8*)(bB + (size_t)kb * 512);
            const int coll = (wave * 2 + ntl) * 16 + l15;
            const float bvv = be1[ntg * 16 + l15];
#pragma unroll
            for (int mt = 0; mt < 2; ++mt) {
                f32x4 acc = (f32x4){0.f, 0.f, 0.f, 0.f};
#pragma unroll
                for (int kb = 0; kb < 4; ++kb)
                    acc = __builtin_amdgcn_mfma_f32_16x16x32_bf16(aT[mt][kb], w[kb], acc, 0, 0, 0);
#pragma unroll
                for (int r = 0; r < 4; ++r)
                    sH1[(mt * 16 + quad * 4 + r) * 136 + coll] = f2bs(fmaxf(acc[r] + bvv, 0.f));
            }
        }
        __syncthreads();
        // H2 += H1q @ we2[q*128:+128, :]
        {
            short8 aH[2][4];
#pragma unroll
            for (int mt = 0; mt < 2; ++mt)
#pragma unroll
                for (int kb = 0; kb < 4; ++kb)
                    aH[mt][kb] = *(const short8*)(sH1 + (mt * 16 + l15) * 136 + quad * 8 + kb * 32);
#pragma unroll
            for (int ntl = 0; ntl < 2; ++ntl) {
                const int nt = wave * 2 + ntl;
                const short* bB = we2P + ((size_t)(nt * 16 + q * 4) * 64 + lane) * 8;
                short8 w[4];
#pragma unroll
                for (int kb = 0; kb < 4; ++kb) w[kb] = *(const short8*)(bB + (size_t)kb * 512);
#pragma unroll
                for (int mt = 0; mt < 2; ++mt) {
#pragma unroll
                    for (int kb = 0; kb < 4; ++kb)
                        accE[ntl * 2 + mt] = __builtin_amdgcn_mfma_f32_16x16x32_bf16(
                            aH[mt][kb], w[kb], accE[ntl * 2 + mt], 0, 0, 0);
                }
            }
        }
        __syncthreads();
    }
    // epilogue -> sH2 f32 (over dead sTb/sYb region)
#pragma unroll
    for (int ntl = 0; ntl < 2; ++ntl)
#pragma unroll
        for (int mt = 0; mt < 2; ++mt) {
            const int col = (wave * 2 + ntl) * 16 + l15;
            const float bvv = be2[col];
#pragma unroll
            for (int r = 0; r < 4; ++r)
                sH2[(mt * 16 + quad * 4 + r) * 132 + col] = accE[ntl * 2 + mt][r] + bvv;
        }
    __syncthreads();

    // ---- LN2 -> global ----
    for (int rr = 0; rr < 8; ++rr) {
        int row = wave * 8 + rr;
        float v0 = bs2f(sEb[row * 136 + lane]) + sH2[row * 132 + lane];
        float v1 = bs2f(sEb[row * 136 + lane + 64]) + sH2[row * 132 + lane + 64];
        float s1 = v0 + v1, s2 = v0 * v0 + v1 * v1;
        for (int off = 32; off; off >>= 1) {
            s1 += __shfl_down(s1, off);
            s2 += __shfl_down(s2, off);
        }
        s1 = __shfl(s1, 0); s2 = __shfl(s2, 0);
        float mean = s1 * 0.0078125f;
        float var = s2 * 0.0078125f - mean * mean;
        float rstd = rsqrtf(var + 1e-5f);
        size_t o = (size_t)(r0 + row) * 128;
        eout[o + lane]      = (v0 - mean) * rstd * g0 + bn0;
        eout[o + lane + 64] = (v1 - mean) * rstd * g1 + bn1;
    }
}

extern "C" void kernel_launch(void* const* d_in, const int* in_sizes, int n_in,
                              void* d_out, int out_size, void* d_ws, size_t ws_size,
                              hipStream_t stream) {
    const float* x   = (const float*)d_in[0];
    const float* e   = (const float*)d_in[1];
    const float* wq  = (const float*)d_in[2];
    const float* wk  = (const float*)d_in[3];
    const float* wv  = (const float*)d_in[4];
    const float* wem = (const float*)d_in[5];
    const float* wea = (const float*)d_in[6];
    const float* wxo = (const float*)d_in[7];
    const float* weo = (const float*)d_in[8];
    const float* wx1 = (const float*)d_in[9];
    const float* wx2 = (const float*)d_in[10];
    const float* we1 = (const float*)d_in[11];
    const float* we2 = (const float*)d_in[12];
    const float* bq  = (const float*)d_in[13];
    const float* bk  = (const float*)d_in[14];
    const float* bv  = (const float*)d_in[15];
    const float* bem = (const float*)d_in[16];
    const float* bea = (const float*)d_in[17];
    const float* bxo = (const float*)d_in[18];
    const float* beo = (const float*)d_in[19];
    const float* bx1 = (const float*)d_in[20];
    const float* bx2 = (const float*)d_in[21];
    const float* be1 = (const float*)d_in[22];
    const float* be2 = (const float*)d_in[23];
    const float* gnx = (const float*)d_in[24];
    const float* bnx = (const float*)d_in[25];
    const float* gne = (const float*)d_in[26];
    const float* bne = (const float*)d_in[27];

    float* out = (float*)d_out;  // x_out (262144) then e_out (16777216)

    float* ws = (float*)d_ws;
    float* Qb = ws;               // 262144 f32
    float* Kb = Qb + 262144;      // 262144 f32
    short* base = (short*)(Kb + 262144);
    short* wqP  = base;           // 65536
    short* wkP  = wqP + 65536;
    short* wvP  = wkP + 65536;
    short* wxoP = wvP + 65536;
    short* wx1P = wxoP + 65536;   // 262144
    short* wx2P = wx1P + 262144;  // 262144
    short* wemP = wx2P + 262144;  // 32768
    short* weaP = wemP + 32768;
    short* weoP = weaP + 32768;
    short* we1P = weoP + 32768;   // 65536
    short* we2P = we1P + 65536;   // 65536

    // ---- one pack launch for all 11 weights ----
    PackArgs pa;
    const float* Ws[11] = {wq, wk, wv, wxo, wx1, wx2, wem, wea, weo, we1, we2};
    short* Wps[11] = {wqP, wkP, wvP, wxoP, wx1P, wx2P, wemP, weaP, weoP, we1P, we2P};
    int Ks[11] = {256, 256, 256, 256, 256, 1024, 128, 128, 256, 128, 512};
    int Ns[11] = {256, 256, 256, 256, 1024, 256, 256, 256, 128, 512, 128};
    int acc = 0;
    for (int i = 0; i < 11; ++i) {
        pa.W[i] = Ws[i];
        pa.Wp[i] = Wps[i];
        pa.kdiv[i] = Ks[i] >> 5;
        pa.N[i] = Ns[i];
        pa.start[i] = acc;
        acc += (Ns[i] >> 4) * (Ks[i] >> 5) * 64;
    }
    pa.start[11] = acc;
    pack_all<<<(acc + 255) / 256, 256, 0, stream>>>(pa);

    // ---- Q/K GEMM (only cross-path dependency) ----
    qk_gemm<<<128, 256, 0, stream>>>(x, wqP, wkP, bq, bk, Qb, Kb);

    // ---- fused main: 64 x-rest blocks (first, overlap) + 4096 e-path ----
    fused_main<<<4160, 256, 0, stream>>>(
        x, e, Qb, Kb, wvP, wxoP, wx1P, wx2P, wemP, weaP, weoP, we1P, we2P,
        bv, bxo, bx1, bx2, bem, bea, beo, be1, be2,
        gnx, bnx, gne, bne, out, out + 262144);
}